// Round 14
// baseline (65.243 us; speedup 1.0000x reference)
//
#include <hip/hip_runtime.h>
#include <math.h>

#define VOCAB   50265
#define D       768
#define N_NEW   200
#define N_NODES 199
#define N_EDGES 1024
#define LEAKY   0.2f

typedef float f4 __attribute__((ext_vector_type(4)));

// ---- GEMM split-K config ----
#define ROW_T 4
#define KC    8
#define KLEN  96                  // 768/KC
#define NROWT 50                  // ceil(199/4)
#define NCH   (KC * 3)            // svp/dvp slots per row (24)
#define NB_GEMM (NROWT * 3 * KC)  // 1200

// ---------------- L1: hybrid — gather blocks FIRST, gemm blocks last
__global__ __launch_bounds__(256) void hybrid_kernel(
    const int* __restrict__ x, const float* __restrict__ orig_emb,
    const float* __restrict__ new_emb, const float* __restrict__ W,
    const float* __restrict__ a_src, const float* __restrict__ a_dst,
    float* __restrict__ partial, float* __restrict__ svp, float* __restrict__ dvp,
    float* __restrict__ out, int* __restrict__ gcnt, int* __restrict__ glist,
    int nb_gather, int ntok)
{
    const int tid = threadIdx.x;
    const int bid = blockIdx.x;

    if (bid >= nb_gather) {
        // ================= GEMM partial (dispatched last) =================
        __shared__ float fts[ROW_T][KLEN];
        __shared__ float rS[ROW_T][4], rD[ROW_T][4];
        const int gb   = bid - nb_gather;
        const int rowt = gb % NROWT;
        const int colt = (gb / NROWT) % 3;
        const int kc   = gb / (NROWT * 3);
        const int row0 = rowt * ROW_T;
        const int col  = colt * 256 + tid;
        const int k0   = kc * KLEN;
        const int lane = tid & 63, wid = tid >> 6;

        for (int i = tid; i < ROW_T * KLEN; i += 256) {
            int r  = i / KLEN;
            int kk = i - r * KLEN;
            int row = row0 + r;
            fts[r][kk] = (row < N_NODES) ? new_emb[(size_t)(1 + row) * D + k0 + kk] : 0.f;
        }
        __syncthreads();

        float acc[ROW_T] = {0.f, 0.f, 0.f, 0.f};
        #pragma unroll 4
        for (int kk = 0; kk < KLEN; ++kk) {
            float w = W[(size_t)(k0 + kk) * D + col];
            #pragma unroll
            for (int r = 0; r < ROW_T; ++r)
                acc[r] = fmaf(fts[r][kk], w, acc[r]);
        }

        const size_t base = ((size_t)kc * N_NODES) * D + col;
        #pragma unroll
        for (int r = 0; r < ROW_T; ++r)
            if (row0 + r < N_NODES) partial[base + (size_t)(row0 + r) * D] = acc[r];

        const float as = a_src[col];
        const float ad = a_dst[col];
        #pragma unroll
        for (int r = 0; r < ROW_T; ++r) {
            float ps = acc[r] * as;
            float pd = acc[r] * ad;
            #pragma unroll
            for (int off = 32; off; off >>= 1) {
                ps += __shfl_down(ps, off, 64);
                pd += __shfl_down(pd, off, 64);
            }
            if (lane == 0) { rS[r][wid] = ps; rD[r][wid] = pd; }
        }
        __syncthreads();
        if (tid < ROW_T) {
            const int row = row0 + tid;
            if (row < N_NODES) {
                const int slot = row * NCH + kc * 3 + colt;
                svp[slot] = rS[tid][0] + rS[tid][1] + rS[tid][2] + rS[tid][3];
                dvp[slot] = rD[tid][0] + rD[tid][1] + rD[tid][2] + rD[tid][3];
            }
        }
        return;
    }

    // ================= Gather (non-graph tokens), dispatched first =========
    const int token = bid * 4 + (tid >> 6);
    if (token >= ntok) return;
    const int lane = tid & 63;
    const int idx = x[token];

    if (idx >= VOCAB && idx < VOCAB + N_NODES) {
        if (lane == 0) {
            int pos = atomicAdd(gcnt, 1);
            glist[pos] = token;
        }
        return;
    }

    const f4* src = (idx < VOCAB)
        ? (const f4*)(orig_emb + (size_t)idx * D)
        : (const f4*)(new_emb + (size_t)N_NEW * D);

    f4* dst = (f4*)(out + (size_t)token * D);
    f4 v0 = src[lane];
    f4 v1 = src[lane + 64];
    f4 v2 = src[lane + 128];
    __builtin_nontemporal_store(v0, &dst[lane]);
    __builtin_nontemporal_store(v1, &dst[lane + 64]);
    __builtin_nontemporal_store(v2, &dst[lane + 128]);
}

// ---------------- L2: per-node softmax + aggregate (one block per node)
__global__ __launch_bounds__(256) void softagg_kernel(
    const int* __restrict__ edge_index, const float* __restrict__ svp,
    const float* __restrict__ dvp, const float* __restrict__ partial,
    const float* __restrict__ new_emb, float* __restrict__ gfeats)
{
    __shared__ float sv_l[N_NODES], dv_l[N_NODES];
    __shared__ float e[N_EDGES];
    __shared__ short ssrc[N_EDGES];
    __shared__ short ml[N_EDGES];
    __shared__ int   wsum[4];
    __shared__ int   s_total;
    const int n   = blockIdx.x;
    const int tid = threadIdx.x;
    const int lane = tid & 63, wid = tid >> 6;

    for (int i = tid; i < N_NODES; i += 256) {
        float s = 0.f, d = 0.f;
        #pragma unroll
        for (int q = 0; q < NCH; ++q) {
            s += svp[i * NCH + q];
            d += dvp[i * NCH + q];
        }
        sv_l[i] = s;
        dv_l[i] = d;
    }
    __syncthreads();

    const int4 se = ((const int4*)edge_index)[tid];
    const int4 de = ((const int4*)(edge_index + N_EDGES))[tid];
    const int srcs[4] = { se.x, se.y, se.z, se.w };
    const int dsts[4] = { de.x, de.y, de.z, de.w };

    int mycnt = 0;
    #pragma unroll
    for (int j = 0; j < 4; ++j) {
        const int k = 4 * tid + j;
        float ev = sv_l[srcs[j]] + dv_l[dsts[j]];
        e[k] = ev > 0.f ? ev : LEAKY * ev;
        ssrc[k] = (short)srcs[j];
        if (dsts[j] == n) ++mycnt;
    }

    int pre = mycnt;
    #pragma unroll
    for (int off = 1; off < 64; off <<= 1) {
        int v = __shfl_up(pre, off, 64);
        if (lane >= off) pre += v;
    }
    if (lane == 63) wsum[wid] = pre;
    __syncthreads();
    int woff = 0;
    for (int w = 0; w < wid; ++w) woff += wsum[w];
    int base = woff + pre - mycnt;
    #pragma unroll
    for (int j = 0; j < 4; ++j) {
        if (dsts[j] == n) ml[base++] = (short)(4 * tid + j);
    }
    if (tid == 255) s_total = woff + pre;
    __syncthreads();

    const int c = s_total;

    float mx = -INFINITY;
    for (int p = 0; p < c; ++p) mx = fmaxf(mx, e[ml[p]]);
    float dn = 0.f;
    for (int p = 0; p < c; ++p) dn += expf(e[ml[p]] - mx);
    const float inv = 1.f / fmaxf(dn, 1e-9f);

    const size_t kcstride = (size_t)N_NODES * D;
    float a0 = 0.f, a1 = 0.f, a2 = 0.f;
    for (int p = 0; p < c; ++p) {
        const int k = ml[p];
        const float a = expf(e[k] - mx) * inv;
        const float* pb = partial + (size_t)ssrc[k] * D;
        float h0 = 0.f, h1 = 0.f, h2 = 0.f;
        #pragma unroll
        for (int q = 0; q < KC; ++q) {
            h0 += pb[q * kcstride + tid];
            h1 += pb[q * kcstride + tid + 256];
            h2 += pb[q * kcstride + tid + 512];
        }
        a0 = fmaf(a, h0, a0);
        a1 = fmaf(a, h1, a1);
        a2 = fmaf(a, h2, a2);
    }
    const float* f = new_emb + (size_t)(1 + n) * D;
    float e0 = a0 > 0.f ? a0 : expf(a0) - 1.f;
    float e1 = a1 > 0.f ? a1 : expf(a1) - 1.f;
    float e2 = a2 > 0.f ? a2 : expf(a2) - 1.f;
    gfeats[(size_t)n * D + tid]       = e0 + f[tid];
    gfeats[(size_t)n * D + tid + 256] = e1 + f[tid + 256];
    gfeats[(size_t)n * D + tid + 512] = e2 + f[tid + 512];
}

// ---------------- L3: fixup — copy gfeats rows for recorded graph tokens
#define FIX_BLOCKS 64
__global__ __launch_bounds__(256) void fixup_kernel(
    const int* __restrict__ x, const float* __restrict__ gfeats,
    const int* __restrict__ gcnt, const int* __restrict__ glist,
    float* __restrict__ out)
{
    const int lane = threadIdx.x & 63;
    const int wid  = threadIdx.x >> 6;
    const int cnt  = *gcnt;

    for (int i = blockIdx.x * 4 + wid; i < cnt; i += FIX_BLOCKS * 4) {
        const int token = glist[i];
        const int n = x[token] - VOCAB;
        const f4* src = (const f4*)(gfeats + (size_t)n * D);
        f4* dst = (f4*)(out + (size_t)token * D);
        f4 v0 = src[lane];
        f4 v1 = src[lane + 64];
        f4 v2 = src[lane + 128];
        __builtin_nontemporal_store(v0, &dst[lane]);
        __builtin_nontemporal_store(v1, &dst[lane + 64]);
        __builtin_nontemporal_store(v2, &dst[lane + 128]);
    }
}

extern "C" void kernel_launch(void* const* d_in, const int* in_sizes, int n_in,
                              void* d_out, int out_size, void* d_ws, size_t ws_size,
                              hipStream_t stream) {
    const int*   x        = (const int*)  d_in[0];
    const float* orig_emb = (const float*)d_in[1];
    const float* new_emb  = (const float*)d_in[2];
    const float* W        = (const float*)d_in[3];
    const float* a_src    = (const float*)d_in[4];
    const float* a_dst    = (const float*)d_in[5];
    const int*   edge_idx = (const int*)  d_in[6];
    float* out = (float*)d_out;

    // workspace layout
    int*   gcnt    = (int*)d_ws;                               // counter
    float* partial = (float*)((char*)d_ws + 256);              // KC*199*768
    float* svp     = partial + (size_t)KC * N_NODES * D;       // 199*NCH
    float* dvp     = svp + N_NODES * NCH;                      // 199*NCH
    float* gfeats  = dvp + N_NODES * NCH;                      // 199*768
    int*   glist   = (int*)(gfeats + (size_t)N_NODES * D);     // up to ntok

    const int ntok = in_sizes[0];                              // 32768
    const int nb_gather = (ntok + 3) / 4;                      // 8192
    const int nblocks = nb_gather + NB_GEMM;                   // 8192 + 1200

    hipMemsetAsync(gcnt, 0, 16, stream);
    hybrid_kernel<<<nblocks, 256, 0, stream>>>(
        x, orig_emb, new_emb, W, a_src, a_dst,
        partial, svp, dvp, out, gcnt, glist, nb_gather, ntok);
    softagg_kernel<<<N_NODES, 256, 0, stream>>>(
        edge_idx, svp, dvp, partial, new_emb, gfeats);
    fixup_kernel<<<FIX_BLOCKS, 256, 0, stream>>>(
        x, gfeats, gcnt, glist, out);
}

// Round 15
// 51.592 us; speedup vs baseline: 1.2646x; 1.2646x over previous
//
#include <hip/hip_runtime.h>
#include <math.h>

#define VOCAB   50265
#define D       768
#define N_NEW   200
#define N_NODES 199
#define N_EDGES 1024
#define LEAKY   0.2f

typedef float f4 __attribute__((ext_vector_type(4)));

// ---- GEMM split-K config ----
#define ROW_T 4
#define KC    8
#define KLEN  96                  // 768/KC
#define NROWT 50                  // ceil(199/4)
#define NCH   (KC * 3)            // svp/dvp slots per row (24)
#define NB_GEMM (NROWT * 3 * KC)  // 1200

// ---------------- L1: hybrid — gemm blocks first (R11-proven), then gather
__global__ __launch_bounds__(256) void hybrid_kernel(
    const int* __restrict__ x, const float* __restrict__ orig_emb,
    const float* __restrict__ new_emb, const float* __restrict__ W,
    const float* __restrict__ a_src, const float* __restrict__ a_dst,
    float* __restrict__ partial, float* __restrict__ svp, float* __restrict__ dvp,
    float* __restrict__ out, int ntok)
{
    const int tid = threadIdx.x;
    const int bid = blockIdx.x;

    if (bid < NB_GEMM) {
        // ================= GEMM partial =================
        __shared__ float fts[ROW_T][KLEN];
        __shared__ float rS[ROW_T][4], rD[ROW_T][4];
        const int rowt = bid % NROWT;
        const int colt = (bid / NROWT) % 3;
        const int kc   = bid / (NROWT * 3);
        const int row0 = rowt * ROW_T;
        const int col  = colt * 256 + tid;
        const int k0   = kc * KLEN;
        const int lane = tid & 63, wid = tid >> 6;

        for (int i = tid; i < ROW_T * KLEN; i += 256) {
            int r  = i / KLEN;
            int kk = i - r * KLEN;
            int row = row0 + r;
            fts[r][kk] = (row < N_NODES) ? new_emb[(size_t)(1 + row) * D + k0 + kk] : 0.f;
        }
        __syncthreads();

        float acc[ROW_T] = {0.f, 0.f, 0.f, 0.f};
        #pragma unroll 4
        for (int kk = 0; kk < KLEN; ++kk) {
            float w = W[(size_t)(k0 + kk) * D + col];
            #pragma unroll
            for (int r = 0; r < ROW_T; ++r)
                acc[r] = fmaf(fts[r][kk], w, acc[r]);
        }

        const size_t base = ((size_t)kc * N_NODES) * D + col;
        #pragma unroll
        for (int r = 0; r < ROW_T; ++r)
            if (row0 + r < N_NODES) partial[base + (size_t)(row0 + r) * D] = acc[r];

        const float as = a_src[col];
        const float ad = a_dst[col];
        #pragma unroll
        for (int r = 0; r < ROW_T; ++r) {
            float ps = acc[r] * as;
            float pd = acc[r] * ad;
            #pragma unroll
            for (int off = 32; off; off >>= 1) {
                ps += __shfl_down(ps, off, 64);
                pd += __shfl_down(pd, off, 64);
            }
            if (lane == 0) { rS[r][wid] = ps; rD[r][wid] = pd; }
        }
        __syncthreads();
        if (tid < ROW_T) {
            const int row = row0 + tid;
            if (row < N_NODES) {
                const int slot = row * NCH + kc * 3 + colt;
                svp[slot] = rS[tid][0] + rS[tid][1] + rS[tid][2] + rS[tid][3];
                dvp[slot] = rD[tid][0] + rD[tid][1] + rD[tid][2] + rD[tid][3];
            }
        }
        return;
    }

    // ================= Gather (non-graph tokens) =================
    const int token = (bid - NB_GEMM) * 4 + (tid >> 6);
    if (token >= ntok) return;
    const int lane = tid & 63;
    const int idx = x[token];

    if (idx >= VOCAB && idx < VOCAB + N_NODES) return;   // fixup handles these

    const f4* src = (idx < VOCAB)
        ? (const f4*)(orig_emb + (size_t)idx * D)
        : (const f4*)(new_emb + (size_t)N_NEW * D);

    f4* dst = (f4*)(out + (size_t)token * D);
    f4 v0 = src[lane];
    f4 v1 = src[lane + 64];
    f4 v2 = src[lane + 128];
    __builtin_nontemporal_store(v0, &dst[lane]);
    __builtin_nontemporal_store(v1, &dst[lane + 64]);
    __builtin_nontemporal_store(v2, &dst[lane + 128]);
}

// ---------------- L2: per-node softmax + aggregate (one block per node)
__global__ __launch_bounds__(256) void softagg_kernel(
    const int* __restrict__ edge_index, const float* __restrict__ svp,
    const float* __restrict__ dvp, const float* __restrict__ partial,
    const float* __restrict__ new_emb, float* __restrict__ gfeats)
{
    __shared__ float sv_l[N_NODES], dv_l[N_NODES];
    __shared__ float e[N_EDGES];
    __shared__ short ssrc[N_EDGES];
    __shared__ short ml[N_EDGES];
    __shared__ int   wsum[4];
    __shared__ int   s_total;
    const int n   = blockIdx.x;
    const int tid = threadIdx.x;
    const int lane = tid & 63, wid = tid >> 6;

    for (int i = tid; i < N_NODES; i += 256) {
        float s = 0.f, d = 0.f;
        #pragma unroll
        for (int q = 0; q < NCH; ++q) {
            s += svp[i * NCH + q];
            d += dvp[i * NCH + q];
        }
        sv_l[i] = s;
        dv_l[i] = d;
    }
    __syncthreads();

    const int4 se = ((const int4*)edge_index)[tid];
    const int4 de = ((const int4*)(edge_index + N_EDGES))[tid];
    const int srcs[4] = { se.x, se.y, se.z, se.w };
    const int dsts[4] = { de.x, de.y, de.z, de.w };

    int mycnt = 0;
    #pragma unroll
    for (int j = 0; j < 4; ++j) {
        const int k = 4 * tid + j;
        float ev = sv_l[srcs[j]] + dv_l[dsts[j]];
        e[k] = ev > 0.f ? ev : LEAKY * ev;
        ssrc[k] = (short)srcs[j];
        if (dsts[j] == n) ++mycnt;
    }

    int pre = mycnt;
    #pragma unroll
    for (int off = 1; off < 64; off <<= 1) {
        int v = __shfl_up(pre, off, 64);
        if (lane >= off) pre += v;
    }
    if (lane == 63) wsum[wid] = pre;
    __syncthreads();
    int woff = 0;
    for (int w = 0; w < wid; ++w) woff += wsum[w];
    int base = woff + pre - mycnt;
    #pragma unroll
    for (int j = 0; j < 4; ++j) {
        if (dsts[j] == n) ml[base++] = (short)(4 * tid + j);
    }
    if (tid == 255) s_total = woff + pre;
    __syncthreads();

    const int c = s_total;

    float mx = -INFINITY;
    for (int p = 0; p < c; ++p) mx = fmaxf(mx, e[ml[p]]);
    float dn = 0.f;
    for (int p = 0; p < c; ++p) dn += expf(e[ml[p]] - mx);
    const float inv = 1.f / fmaxf(dn, 1e-9f);

    const size_t kcstride = (size_t)N_NODES * D;
    float a0 = 0.f, a1 = 0.f, a2 = 0.f;
    for (int p = 0; p < c; ++p) {
        const int k = ml[p];
        const float a = expf(e[k] - mx) * inv;
        const float* pb = partial + (size_t)ssrc[k] * D;
        float h0 = 0.f, h1 = 0.f, h2 = 0.f;
        #pragma unroll
        for (int q = 0; q < KC; ++q) {
            h0 += pb[q * kcstride + tid];
            h1 += pb[q * kcstride + tid + 256];
            h2 += pb[q * kcstride + tid + 512];
        }
        a0 = fmaf(a, h0, a0);
        a1 = fmaf(a, h1, a1);
        a2 = fmaf(a, h2, a2);
    }
    const float* f = new_emb + (size_t)(1 + n) * D;
    float e0 = a0 > 0.f ? a0 : expf(a0) - 1.f;
    float e1 = a1 > 0.f ? a1 : expf(a1) - 1.f;
    float e2 = a2 > 0.f ? a2 : expf(a2) - 1.f;
    gfeats[(size_t)n * D + tid]       = e0 + f[tid];
    gfeats[(size_t)n * D + tid + 256] = e1 + f[tid + 256];
    gfeats[(size_t)n * D + tid + 512] = e2 + f[tid + 512];
}

// ---------------- L3: fixup — ballot-scan x, copy gfeats rows (no atomics)
// 512 waves, each owns 64 consecutive tokens: coalesced x load + ballot.
#define FIX_BLOCKS 128
__global__ __launch_bounds__(256) void fixup_kernel(
    const int* __restrict__ x, const float* __restrict__ gfeats,
    float* __restrict__ out, int ntok)
{
    const int lane = threadIdx.x & 63;
    const int gw   = blockIdx.x * 4 + (threadIdx.x >> 6);   // global wave id
    const int tok0 = gw * 64;
    if (tok0 >= ntok) return;

    const int idx = x[tok0 + lane];
    unsigned long long mask = __ballot(idx >= VOCAB && idx < VOCAB + N_NODES);

    while (mask) {
        const int b = __ffsll((long long)mask) - 1;
        mask &= mask - 1;
        const int token = tok0 + b;
        const int n = __shfl(idx, b, 64) - VOCAB;
        const f4* src = (const f4*)(gfeats + (size_t)n * D);
        f4* dst = (f4*)(out + (size_t)token * D);
        f4 v0 = src[lane];
        f4 v1 = src[lane + 64];
        f4 v2 = src[lane + 128];
        __builtin_nontemporal_store(v0, &dst[lane]);
        __builtin_nontemporal_store(v1, &dst[lane + 64]);
        __builtin_nontemporal_store(v2, &dst[lane + 128]);
    }
}

extern "C" void kernel_launch(void* const* d_in, const int* in_sizes, int n_in,
                              void* d_out, int out_size, void* d_ws, size_t ws_size,
                              hipStream_t stream) {
    const int*   x        = (const int*)  d_in[0];
    const float* orig_emb = (const float*)d_in[1];
    const float* new_emb  = (const float*)d_in[2];
    const float* W        = (const float*)d_in[3];
    const float* a_src    = (const float*)d_in[4];
    const float* a_dst    = (const float*)d_in[5];
    const int*   edge_idx = (const int*)  d_in[6];
    float* out = (float*)d_out;

    // workspace layout (all fully written before read; no init needed)
    float* partial = (float*)d_ws;                             // KC*199*768
    float* svp     = partial + (size_t)KC * N_NODES * D;       // 199*NCH
    float* dvp     = svp + N_NODES * NCH;                      // 199*NCH
    float* gfeats  = dvp + N_NODES * NCH;                      // 199*768

    const int ntok = in_sizes[0];                              // 32768
    const int nblocks = NB_GEMM + (ntok + 3) / 4;              // 1200 + 8192

    hybrid_kernel<<<nblocks, 256, 0, stream>>>(
        x, orig_emb, new_emb, W, a_src, a_dst,
        partial, svp, dvp, out, ntok);
    softagg_kernel<<<N_NODES, 256, 0, stream>>>(
        edge_idx, svp, dvp, partial, new_emb, gfeats);
    fixup_kernel<<<FIX_BLOCKS, 256, 0, stream>>>(
        x, gfeats, out, ntok);
}